// Round 18
// baseline (662.079 us; speedup 1.0000x reference)
//
#include <hip/hip_runtime.h>
#include <hip/hip_bf16.h>

typedef __bf16 bf16x8 __attribute__((ext_vector_type(8)));
typedef float f32x4 __attribute__((ext_vector_type(4)));

__device__ __forceinline__ unsigned short f2bf(float x) {
  union { float f; unsigned int u; } v; v.f = x;
  unsigned int r = (v.u + 0x7FFFu + ((v.u >> 16) & 1u)) >> 16;
  return (unsigned short)r;
}
__device__ __forceinline__ float bf2f(unsigned short u) {
  union { unsigned int u; float f; } v; v.u = ((unsigned int)u) << 16;
  return v.f;
}

// feats [N][16] f32 -> [N][16] bf16 COMPACT (row N zeroed separately = zrow)
__global__ void cvt_feats_kernel(const float* __restrict__ f, unsigned short* __restrict__ fb, int n16) {
  int t = blockIdx.x * 256 + threadIdx.x;
  if (t >= n16) return;
  fb[t] = f2bf(f[t]);
}

// Pack W[k][CI][CO] f32 into MFMA B-fragment order (CI>=32 path, conv2/conv3)
__global__ void pack_w_kernel(const float* __restrict__ W, unsigned short* __restrict__ Wp,
                              int CI, int CO, int NT, int KK) {
  int t = blockIdx.x * 256 + threadIdx.x;
  int total = 27 * NT * KK * 512;
  if (t >= total) return;
  int j = t & 7, l = (t >> 3) & 63;
  int g = t >> 9;
  int kk = g % KK; g /= KK;
  int nt = g % NT; int k = g / NT;
  int kg = kk * 32 + ((l >> 4) * 8) + j;
  int c = nt * 16 + (l & 15);
  float v = (kg < CI) ? W[((size_t)k * CI + kg) * CO + c] : 0.0f;
  Wp[t] = f2bf(v);
}

// Paired pack for conv1 (CI=16): tile g holds K-rows 0-15 = W[2g], 16-31 = W[2g+1].
__global__ void pack_w_paired_kernel(const float* __restrict__ W, unsigned short* __restrict__ Wp,
                                     int CO, int NT) {
  int t = blockIdx.x * 256 + threadIdx.x;
  int total = 14 * NT * 512;
  if (t >= total) return;
  int j = t & 7, l = (t >> 3) & 63;
  int g = t >> 9;
  int nt = g % NT; int gp = g / NT;
  int kg = ((l >> 4) * 8) + j;
  int k = 2 * gp + (kg >= 16 ? 1 : 0);
  int ci = kg & 15;
  int c = nt * 16 + (l & 15);
  float v = (k <= 26) ? W[((size_t)k * 16 + ci) * CO + c] : 0.0f;
  Wp[t] = f2bf(v);
}

// tab[k][o] = input index (scatter from pair lists; unique per (k,o) by construction)
__global__ void build_table_kernel(const int* __restrict__ pin, const int* __restrict__ pout,
                                   int P, int maxo, int* __restrict__ tab,
                                   const int* __restrict__ n_ptr, int n_cap) {
  int p = blockIdx.x * 256 + threadIdx.x;
  if (p >= P) return;
  int k = blockIdx.y;
  int n = n_cap;
  if (n_ptr) { int nv = n_ptr[0]; if (nv < n) n = nv; }
  size_t e = (size_t)k * P + p;
  int o = pout[e];
  if (o < n) tab[(size_t)k * maxo + o] = pin[e];
}

// ---- conv3 parity-class machinery: for the inverse conv, ALL valid ks of an
// output row share one per-dim parity (c_i = 2*c_j + k  =>  k === c_i mod 2),
// so rows sorted by the 8 parity classes (+1 empty class) give perfect
// wave-level ballot skipping: a wave only works its class's ~3.4 ks of 27.

// class per row from any valid k's parity; also global histogram.
__global__ void class_hist_kernel(const int* __restrict__ tab, int maxo, int n,
                                  int* __restrict__ cls, int* __restrict__ hist) {
  __shared__ int lh[9];
  if (threadIdx.x < 9) lh[threadIdx.x] = 0;
  __syncthreads();
  int i = blockIdx.x * 256 + threadIdx.x;
  if (i < n) {
    int c = 8;
#pragma unroll
    for (int k = 0; k < 27; ++k) {
      if (tab[(size_t)k * maxo + i] >= 0) {
        int kz = k / 9, ky = (k / 3) % 3, kx = k % 3;
        c = ((kz & 1) << 2) | ((ky & 1) << 1) | (kx & 1);
      }
    }
    cls[i] = c;
    atomicAdd(&lh[c], 1);
  }
  __syncthreads();
  if (threadIdx.x < 9) atomicAdd(&hist[threadIdx.x], lh[threadIdx.x]);
}

__global__ void prefix9_kernel(const int* __restrict__ hist, int* __restrict__ cursor) {
  if (threadIdx.x == 0) {
    int s = 0;
    for (int c = 0; c < 9; ++c) { cursor[c] = s; s += hist[c]; }
  }
}

// block-local stable scatter into perm (order within class across blocks is
// atomic-order dependent, but output VALUES are row-independent -> deterministic)
__global__ void scatter_kernel(const int* __restrict__ cls, int n,
                               int* __restrict__ cursor, int* __restrict__ perm) {
  __shared__ int lh[9], lbase[9];
  if (threadIdx.x < 9) lh[threadIdx.x] = 0;
  __syncthreads();
  int i = blockIdx.x * 256 + threadIdx.x;
  int c = -1, lrank = 0;
  if (i < n) { c = cls[i]; lrank = atomicAdd(&lh[c], 1); }
  __syncthreads();
  if (threadIdx.x < 9) lbase[threadIdx.x] = atomicAdd(&cursor[threadIdx.x], lh[threadIdx.x]);
  __syncthreads();
  if (c >= 0) perm[lbase[c] + lrank] = i;
}

// Sorted conv3: wave = 32 perm'd same-class rows; per k: tab (1-deep prefetch),
// ballot-skip EVERYTHING (loads included) on inactive ks; no LDS, no barriers.
template<int KK, int NT>
__global__ __launch_bounds__(256, 4) void conv_sorted_kernel(
    const unsigned short* __restrict__ Xb, const unsigned short* __restrict__ Wp,
    const int* __restrict__ tab, int maxo, int zrow,
    const int* __restrict__ perm, int n_rows, float* __restrict__ outf) {
  const int CO = NT * 16;
  const int ROWS = KK * 32;
  int bid = blockIdx.x;
  int w = threadIdx.x >> 6, l = threadIdx.x & 63;
  int wbase = (bid * 4 + w) * 32;
  if (wbase >= n_rows) return;          // per-wave exit OK: no barriers below
  int lr = l & 15, lg = l >> 4;
  int sr0 = wbase + lr, sr1 = wbase + 16 + lr;
  bool ok0 = sr0 < n_rows, ok1 = sr1 < n_rows;
  int row0 = perm[ok0 ? sr0 : (n_rows - 1)];
  int row1 = perm[ok1 ? sr1 : (n_rows - 1)];

  f32x4 acc[2][NT] = {};

  int t0 = ok0 ? tab[row0] : -1;        // k=0
  int t1 = ok1 ? tab[row1] : -1;
#pragma unroll 1
  for (int k = 0; k < 27; ++k) {
    int u0 = -1, u1 = -1;
    if (k < 26) {                       // prefetch tab(k+1)
      u0 = ok0 ? tab[(size_t)(k + 1) * maxo + row0] : -1;
      u1 = ok1 ? tab[(size_t)(k + 1) * maxo + row1] : -1;
    }
    if (__ballot(t0 >= 0 || t1 >= 0) != 0ull) {
      const unsigned short* s0 = Xb + (size_t)(t0 < 0 ? zrow : t0) * ROWS + lg * 8;
      const unsigned short* s1 = Xb + (size_t)(t1 < 0 ? zrow : t1) * ROWS + lg * 8;
      bf16x8 a0[KK], a1[KK];
#pragma unroll
      for (int kk = 0; kk < KK; ++kk) {
        a0[kk] = *reinterpret_cast<const bf16x8*>(s0 + kk * 32);
        a1[kk] = *reinterpret_cast<const bf16x8*>(s1 + kk * 32);
      }
#pragma unroll
      for (int kk = 0; kk < KK; ++kk)
#pragma unroll
        for (int nt = 0; nt < NT; ++nt) {
          bf16x8 b = *reinterpret_cast<const bf16x8*>(
              Wp + ((((size_t)k * NT + nt) * KK + kk) << 9) + l * 8);
          acc[0][nt] = __builtin_amdgcn_mfma_f32_16x16x32_bf16(a0[kk], b, acc[0][nt], 0, 0, 0);
          acc[1][nt] = __builtin_amdgcn_mfma_f32_16x16x32_bf16(a1[kk], b, acc[1][nt], 0, 0, 0);
        }
    }
    t0 = u0; t1 = u1;
  }

#pragma unroll
  for (int mt = 0; mt < 2; ++mt) {
#pragma unroll
    for (int rr = 0; rr < 4; ++rr) {
      int sr = wbase + mt * 16 + lg * 4 + rr;
      if (sr < n_rows) {
        int row = perm[sr];
#pragma unroll
        for (int nt = 0; nt < NT; ++nt)
          outf[(size_t)row * CO + nt * 16 + lr] = acc[mt][nt][rr];
      }
    }
  }
}

// Per-lane tab loads, UNCONDITIONAL (rows pre-clamped; k clamped but load still
// issued) -> vmcnt accounting stays exact. PAIRED: lane's k = 2*step + klb.
#define LDTAB(KC_, TARR) do {                                                    \
    int _k2 = PAIRED ? (2 * (KC_) + klb) : (KC_);                                \
    int _kc = _k2 > 26 ? 26 : _k2;                                               \
    _Pragma("unroll") for (int _m = 0; _m < MT; ++_m) {                          \
      int _t = tab[(size_t)_kc * maxo + rowm[_m]];                               \
      TARR[_m] = (PAIRED && _k2 > 26) ? -1 : _t;                                 \
    }                                                                            \
  } while (0)

// Gather A fragments into AB from tab values TARR; sets D (SKIP only).
#define ISSUE_A(AB, TARR, D) do {                                                \
    if (SKIP) {                                                                  \
      bool _anyv = (TARR[0] >= 0);                                               \
      _Pragma("unroll") for (int _m = 1; _m < MT; ++_m)                          \
        _anyv = _anyv || (TARR[_m] >= 0);                                        \
      D = (__ballot(_anyv) != 0ull);                                             \
    }                                                                            \
    _Pragma("unroll") for (int _m = 0; _m < MT; ++_m) {                          \
      const unsigned short* _s = Xb + (size_t)(TARR[_m] < 0 ? zrow : TARR[_m]) * ROWS + loff; \
      _Pragma("unroll") for (int kk = 0; kk < KK; ++kk)                          \
        AB[_m][kk] = *reinterpret_cast<const bf16x8*>(_s + kk * 32);             \
    }                                                                            \
  } while (0)

// Cooperative LDS staging of the 2 B sub-tiles (KB, KB+1) into PB.
#define STAGE_B2(KB, PB) do {                                                    \
    _Pragma("unroll") for (int _s = 0; _s < 2; ++_s) {                           \
      if ((KB) + _s <= MAXK) {                                                   \
        size_t _kb = (size_t)((KB) + _s) * (size_t)SZ;                           \
        _Pragma("unroll") for (int _j = 0; _j < PER; ++_j) {                     \
          int _c = w * PER + _j;                                                 \
          const unsigned char* _gp = WpB + _kb + (size_t)_c * 1024 + (size_t)l * 16; \
          __builtin_amdgcn_global_load_lds(                                      \
              (const __attribute__((address_space(1))) void*)_gp,                \
              (__attribute__((address_space(3))) void*)((PB) + _s * SZ + _c * 1024), 16, 0, 0); \
        }                                                                        \
      }                                                                          \
    }                                                                            \
  } while (0)

// ds_read B fragments from BCUR + MFMA on buffer AB (per-wave skip if empty).
#define STEP_CORE(BCUR, AB, D) do {                                              \
    if (!SKIP || (D)) {                                                          \
      _Pragma("unroll") for (int kk = 0; kk < KK; ++kk)                          \
        _Pragma("unroll") for (int nt = 0; nt < NT; ++nt) {                      \
          bf16x8 b = *reinterpret_cast<const bf16x8*>(&(BCUR)[(nt * KK + kk) * 1024 + l * 16]); \
          _Pragma("unroll") for (int _m = 0; _m < MT; ++_m)                      \
            acc[_m][nt] = __builtin_amdgcn_mfma_f32_16x16x32_bf16(AB[_m][kk], b, acc[_m][nt], 0, 0, 0); \
        }                                                                        \
    }                                                                            \
  } while (0)

// Counted-vmcnt barrier: stage issued FIRST in group; exactly NW loads issued
// after it; vmcnt(NW) completes the stage while prefetches stay in flight.
#define GROUP_BARRIER(NW) do {                                                   \
    __builtin_amdgcn_sched_barrier(0);                                           \
    asm volatile("s_waitcnt vmcnt(%0)" :: "n"(NW) : "memory");                   \
    __builtin_amdgcn_sched_barrier(0);                                           \
    __builtin_amdgcn_s_barrier();                                                \
  } while (0)

// conv1/conv2 kernel (unchanged from R17).
template<int KK, int NT, int MT, bool SKIP, bool PAIRED>
__global__ __launch_bounds__(256, 3) void conv_mfma_kernel(
    const unsigned short* __restrict__ Xb, const unsigned short* __restrict__ Wp,
    const int* __restrict__ tab, int maxo, int zrow,
    const int* __restrict__ n_ptr, int n_cap,
    unsigned short* __restrict__ outb, float* __restrict__ outf) {
  const int CO = NT * 16;
  const int ROWS = PAIRED ? 16 : KK * 32;
  const int RPW = 16 * MT;
  constexpr int PER = (KK * NT) / 4;
  constexpr int SZ = KK * NT * 1024;
  constexpr int NSTEP = PAIRED ? 14 : 27;
  constexpr int MAXK = NSTEP - 1;
  constexpr int ITERS = PAIRED ? 3 : 6;
  constexpr int TAIL = NSTEP - 4 * ITERS;
  constexpr int NWAIT  = 2 * MT * KK + 2 * MT;
  constexpr int NWAIT0 = 4 * MT * KK + 4 * MT;

  __shared__ __align__(16) unsigned char Blds[2][2][SZ];

  int bid = blockIdx.x;
  { // bijective XCD-aware swizzle (m204)
    int nwg = gridDim.x;
    int q = nwg >> 3, r = nwg & 7;
    int xcd = bid & 7, orig = bid >> 3;
    bid = (xcd < r ? xcd * (q + 1) : r * (q + 1) + (xcd - r) * q) + orig;
  }

  int w = threadIdx.x >> 6, l = threadIdx.x & 63;
  int n_rows = n_cap;
  if (n_ptr) { int nv = n_ptr[0]; if (nv < n_rows) n_rows = nv; }
  if (bid * 4 * RPW >= n_rows) return;
  int lr = l & 15, lg = l >> 4;
  int klb = lg >> 1;
  int loff = PAIRED ? (lg & 1) * 8 : lg * 8;
  int wbase = bid * 4 * RPW + w * RPW;

  int rowm[MT];
#pragma unroll
  for (int m = 0; m < MT; ++m) {
    int r = wbase + m * 16 + lr;
    rowm[m] = r < n_rows ? r : (n_rows - 1);
  }

  const unsigned char* WpB = (const unsigned char*)Wp;

  f32x4 acc[MT][NT] = {};
  bf16x8 aA[MT][KK], aB[MT][KK], aC[MT][KK], aD[MT][KK];
  int t0[MT], t1[MT], t2[MT], t3[MT];
  bool dA = true, dB = true, dC = true, dD = true;

  unsigned char* b0 = &Blds[0][0][0];
  unsigned char* b1 = &Blds[1][0][0];

  LDTAB(0, t0); LDTAB(1, t1); LDTAB(2, t2); LDTAB(3, t3);
  asm volatile("s_waitcnt vmcnt(0)" ::: "memory");
  __builtin_amdgcn_sched_barrier(0);
  STAGE_B2(0, b0);
  __builtin_amdgcn_sched_barrier(0);
  ISSUE_A(aA, t0, dA); ISSUE_A(aB, t1, dB);
  ISSUE_A(aC, t2, dC); ISSUE_A(aD, t3, dD);
  LDTAB(4, t0); LDTAB(5, t1); LDTAB(6, t2); LDTAB(7, t3);
  GROUP_BARRIER(NWAIT0);

#pragma unroll 1
  for (int j = 0; j < ITERS; ++j) {
    int kb = 4 * j;
    STAGE_B2(kb + 2, b1);
    __builtin_amdgcn_sched_barrier(0);
    STEP_CORE(b0 + 0,  aA, dA); ISSUE_A(aA, t0, dA); LDTAB(kb + 8, t0);
    STEP_CORE(b0 + SZ, aB, dB); ISSUE_A(aB, t1, dB); LDTAB(kb + 9, t1);
    GROUP_BARRIER(NWAIT);
    STAGE_B2(kb + 4, b0);
    __builtin_amdgcn_sched_barrier(0);
    STEP_CORE(b1 + 0,  aC, dC); ISSUE_A(aC, t2, dC); LDTAB(kb + 10, t2);
    STEP_CORE(b1 + SZ, aD, dD); ISSUE_A(aD, t3, dD); LDTAB(kb + 11, t3);
    GROUP_BARRIER(NWAIT);
  }

  if (TAIL == 3) {
    STAGE_B2(4 * ITERS + 2, b1);
  }
  STEP_CORE(b0 + 0,  aA, dA);
  STEP_CORE(b0 + SZ, aB, dB);
  if (TAIL == 3) {
    __builtin_amdgcn_sched_barrier(0);
    asm volatile("s_waitcnt vmcnt(0)" ::: "memory");
    __builtin_amdgcn_sched_barrier(0);
    __builtin_amdgcn_s_barrier();
    STEP_CORE(b1 + 0, aC, dC);
  }

#pragma unroll
  for (int mt = 0; mt < MT; ++mt) {
    int r0 = wbase + mt * 16 + lg * 4;
#pragma unroll
    for (int rr = 0; rr < 4; ++rr) {
      int row = r0 + rr;
      if (row < n_rows) {
#pragma unroll
        for (int nt = 0; nt < NT; ++nt) {
          size_t off = (size_t)row * CO + nt * 16 + lr;
          if (outf) outf[off] = acc[mt][nt][rr];
          else outb[off] = f2bf(acc[mt][nt][rr]);
        }
      }
    }
  }
}

// BN stats/apply: R15-proven scalar forms.
__global__ void bn_stats_kernel(const unsigned short* __restrict__ xb,
                                const int* __restrict__ n_ptr, int n_cap,
                                float* __restrict__ stats) {
  int c = threadIdx.x & 63, q = threadIdx.x >> 6;
  int n = n_ptr[0]; if (n > n_cap) n = n_cap;
  float s = 0.f, ss = 0.f;
  for (int r = blockIdx.x * 4 + q; r < n; r += gridDim.x * 4) {
    float v = bf2f(xb[(size_t)r * 64 + c]);
    s += v; ss += v * v;
  }
  __shared__ float ls[8][64];
  ls[q][c] = s; ls[4 + q][c] = ss;
  __syncthreads();
  if (q == 0) {
    s = ls[0][c] + ls[1][c] + ls[2][c] + ls[3][c];
    ss = ls[4][c] + ls[5][c] + ls[6][c] + ls[7][c];
    atomicAdd(&stats[c], s);
    atomicAdd(&stats[64 + c], ss);
  }
}

__global__ void bn_apply_kernel(unsigned short* __restrict__ xb,
                                const int* __restrict__ n_ptr, int n_cap,
                                const float* __restrict__ stats,
                                const float* __restrict__ gamma, const float* __restrict__ beta) {
  int c = threadIdx.x & 63, q = threadIdx.x >> 6;
  int n = n_ptr[0]; if (n > n_cap) n = n_cap;
  float inv_n = 1.f / (float)n;
  float m = stats[c] * inv_n;
  float var = stats[64 + c] * inv_n - m * m;
  float sc = gamma[c] * rsqrtf(var + 1e-5f);
  float sh = beta[c] - m * sc;
  for (int r = blockIdx.x * 4 + q; r < n; r += gridDim.x * 4) {
    size_t off = (size_t)r * 64 + c;
    float v = bf2f(xb[off]) * sc + sh;
    xb[off] = f2bf(v > 0.f ? v : 0.f);
  }
}

extern "C" void kernel_launch(void* const* d_in, const int* in_sizes, int n_in,
                              void* d_out, int out_size, void* d_ws, size_t ws_size,
                              hipStream_t stream) {
  const float* feats  = (const float*)d_in[0];
  const float* W1     = (const float*)d_in[1];
  const float* g1     = (const float*)d_in[2];
  const float* b1     = (const float*)d_in[3];
  const float* W2     = (const float*)d_in[4];
  const float* g2     = (const float*)d_in[5];
  const float* b2     = (const float*)d_in[6];
  const float* W3     = (const float*)d_in[7];
  const int* p1_in    = (const int*)d_in[8];
  const int* p1_out   = (const int*)d_in[9];
  const int* p2_in    = (const int*)d_in[10];
  const int* p2_out   = (const int*)d_in[11];
  const int* d_n1     = (const int*)d_in[12];
  float* out = (float*)d_out;

  const int N  = in_sizes[0] / 16;     // 200000
  const int P1 = in_sizes[8] / 27;
  const int P2 = in_sizes[10] / 27;
  long KP1 = in_sizes[8];
  int n1b = (int)(KP1 < 980100 ? KP1 : 980100);
  int maxo = n1b > N ? n1b : N;

  char* p = (char*)d_ws;
  auto alloc = [&](size_t bytes) -> char* {
    char* r = p; p += (bytes + 255) & ~(size_t)255; return r;
  };
  unsigned short* featsb = (unsigned short*)alloc((size_t)(N + 1) * 16 * 2);
  unsigned short* x1b    = (unsigned short*)alloc((size_t)(n1b + 1) * 64 * 2);
  unsigned short* x2b    = (unsigned short*)alloc((size_t)(n1b + 1) * 64 * 2);
  unsigned short* W1p    = (unsigned short*)alloc((size_t)14 * 4 * 512 * 2);
  unsigned short* W2p    = (unsigned short*)alloc((size_t)27 * 4 * 2 * 512 * 2);
  unsigned short* W3p    = (unsigned short*)alloc((size_t)27 * 2 * 2 * 512 * 2);
  int*   tab   = (int*)alloc((size_t)maxo * 27 * 4);
  float* stats = (float*)alloc(256 * 4);
  int*   cls   = (int*)alloc((size_t)N * 4);
  int*   perm  = (int*)alloc((size_t)N * 4);
  int*   hist  = (int*)alloc(32 * 4);   // hist[9] + cursor[9]
  if ((size_t)(p - (char*)d_ws) > ws_size) return;

  hipMemsetAsync(featsb + (size_t)N * 16, 0, 16 * 2, stream);
  hipMemsetAsync(x1b + (size_t)n1b * 64, 0, 64 * 2, stream);
  hipMemsetAsync(x2b + (size_t)n1b * 64, 0, 64 * 2, stream);
  hipMemsetAsync(stats, 0, 256 * 4, stream);
  hipMemsetAsync(hist, 0, 32 * 4, stream);

  cvt_feats_kernel<<<(N * 16 + 255) / 256, 256, 0, stream>>>(feats, featsb, N * 16);
  pack_w_paired_kernel<<<(14 * 4 * 512 + 255) / 256, 256, 0, stream>>>(W1, W1p, 64, 4);
  pack_w_kernel<<<(27 * 4 * 2 * 512 + 255) / 256, 256, 0, stream>>>(W2, W2p, 64, 64, 4, 2);
  pack_w_kernel<<<(27 * 2 * 2 * 512 + 255) / 256, 256, 0, stream>>>(W3, W3p, 64, 32, 2, 2);

  // ---- stage 1: SparseConv3d 16->64 (sparse tab, PAIRED k: 14 steps) ----
  hipMemsetAsync(tab, 0xFF, (size_t)n1b * 27 * 4, stream);
  build_table_kernel<<<dim3((P1 + 255) / 256, 27), 256, 0, stream>>>(
      p1_in, p1_out, P1, n1b, tab, d_n1, n1b);
  conv_mfma_kernel<1, 4, 2, true, true><<<(n1b + 127) / 128, 256, 0, stream>>>(
      featsb, W1p, tab, n1b, N, d_n1, n1b, x1b, nullptr);
  bn_stats_kernel<<<1024, 256, 0, stream>>>(x1b, d_n1, n1b, stats);
  bn_apply_kernel<<<2048, 256, 0, stream>>>(x1b, d_n1, n1b, stats, g1, b1);

  // ---- stage 2: SubMConv3d 64->64 (dense tab -> SKIP=false) ----
  hipMemsetAsync(tab, 0xFF, (size_t)n1b * 27 * 4, stream);
  build_table_kernel<<<dim3((P2 + 255) / 256, 27), 256, 0, stream>>>(
      p2_in, p2_out, P2, n1b, tab, d_n1, n1b);
  conv_mfma_kernel<2, 4, 2, false, false><<<(n1b + 127) / 128, 256, 0, stream>>>(
      x1b, W2p, tab, n1b, n1b, d_n1, n1b, x2b, nullptr);
  bn_stats_kernel<<<1024, 256, 0, stream>>>(x2b, d_n1, n1b, stats + 128);
  bn_apply_kernel<<<2048, 256, 0, stream>>>(x2b, d_n1, n1b, stats + 128, g2, b2);

  // ---- stage 3: SparseInverseConv3d 64->32, parity-sorted rows ----
  hipMemsetAsync(tab, 0xFF, (size_t)N * 27 * 4, stream);
  build_table_kernel<<<dim3((P1 + 255) / 256, 27), 256, 0, stream>>>(
      p1_out, p1_in, P1, N, tab, nullptr, N);
  class_hist_kernel<<<(N + 255) / 256, 256, 0, stream>>>(tab, N, N, cls, hist);
  prefix9_kernel<<<1, 64, 0, stream>>>(hist, hist + 9);
  scatter_kernel<<<(N + 255) / 256, 256, 0, stream>>>(cls, N, hist + 9, perm);
  conv_sorted_kernel<2, 2><<<(N + 127) / 128, 256, 0, stream>>>(
      x2b, W3p, tab, N, n1b, perm, N, out);
}

// Round 19
// 634.044 us; speedup vs baseline: 1.0442x; 1.0442x over previous
//
#include <hip/hip_runtime.h>
#include <hip/hip_bf16.h>

typedef __bf16 bf16x8 __attribute__((ext_vector_type(8)));
typedef float f32x4 __attribute__((ext_vector_type(4)));

__device__ __forceinline__ unsigned short f2bf(float x) {
  union { float f; unsigned int u; } v; v.f = x;
  unsigned int r = (v.u + 0x7FFFu + ((v.u >> 16) & 1u)) >> 16;
  return (unsigned short)r;
}
__device__ __forceinline__ float bf2f(unsigned short u) {
  union { unsigned int u; float f; } v; v.u = ((unsigned int)u) << 16;
  return v.f;
}

// feats [N][16] f32 -> [N][16] bf16 COMPACT (row N zeroed separately = zrow)
__global__ void cvt_feats_kernel(const float* __restrict__ f, unsigned short* __restrict__ fb, int n16) {
  int t = blockIdx.x * 256 + threadIdx.x;
  if (t >= n16) return;
  fb[t] = f2bf(f[t]);
}

// Pack W[k][CI][CO] f32 into MFMA B-fragment order (CI>=32 path, conv2/conv3):
// Wp[(((k*NT+nt)*KK+kk)*64 + l)*8 + j] = bf16(W[k][kk*32 + (l>>4)*8 + j][nt*16 + (l&15)])
__global__ void pack_w_kernel(const float* __restrict__ W, unsigned short* __restrict__ Wp,
                              int CI, int CO, int NT, int KK) {
  int t = blockIdx.x * 256 + threadIdx.x;
  int total = 27 * NT * KK * 512;
  if (t >= total) return;
  int j = t & 7, l = (t >> 3) & 63;
  int g = t >> 9;
  int kk = g % KK; g /= KK;
  int nt = g % NT; int k = g / NT;
  int kg = kk * 32 + ((l >> 4) * 8) + j;
  int c = nt * 16 + (l & 15);
  float v = (kg < CI) ? W[((size_t)k * CI + kg) * CO + c] : 0.0f;
  Wp[t] = f2bf(v);
}

// Paired pack for conv1 (CI=16): tile g holds K-rows 0-15 = W[2g], 16-31 = W[2g+1].
__global__ void pack_w_paired_kernel(const float* __restrict__ W, unsigned short* __restrict__ Wp,
                                     int CO, int NT) {
  int t = blockIdx.x * 256 + threadIdx.x;
  int total = 14 * NT * 512;
  if (t >= total) return;
  int j = t & 7, l = (t >> 3) & 63;
  int g = t >> 9;
  int nt = g % NT; int gp = g / NT;
  int kg = ((l >> 4) * 8) + j;
  int k = 2 * gp + (kg >= 16 ? 1 : 0);
  int ci = kg & 15;
  int c = nt * 16 + (l & 15);
  float v = (k <= 26) ? W[((size_t)k * 16 + ci) * CO + c] : 0.0f;
  Wp[t] = f2bf(v);
}

// tab[k][o] = input index (scatter from pair lists; unique per (k,o) by construction)
__global__ void build_table_kernel(const int* __restrict__ pin, const int* __restrict__ pout,
                                   int P, int maxo, int* __restrict__ tab,
                                   const int* __restrict__ n_ptr, int n_cap) {
  int p = blockIdx.x * 256 + threadIdx.x;
  if (p >= P) return;
  int k = blockIdx.y;
  int n = n_cap;
  if (n_ptr) { int nv = n_ptr[0]; if (nv < n) n = nv; }
  size_t e = (size_t)k * P + p;
  int o = pout[e];
  if (o < n) tab[(size_t)k * maxo + o] = pin[e];
}

// Per-lane tab loads, UNCONDITIONAL (rows pre-clamped; k clamped but load still
// issued) -> vmcnt accounting at the barrier stays exact. PAIRED: lane's k =
// 2*step + klb; overflow (>26) forces TARR=-1 (zero row + zeroed B half).
#define LDTAB(KC_, TARR) do {                                                    \
    int _k2 = PAIRED ? (2 * (KC_) + klb) : (KC_);                                \
    int _kc = _k2 > 26 ? 26 : _k2;                                               \
    _Pragma("unroll") for (int _m = 0; _m < MT; ++_m) {                          \
      int _t = tab[(size_t)_kc * maxo + rowm[_m]];                               \
      TARR[_m] = (PAIRED && _k2 > 26) ? -1 : _t;                                 \
    }                                                                            \
  } while (0)

// Gather A fragments into AB from tab values TARR; sets D (SKIP only).
// Unconditional: exactly MT*KK loads per call (zrow fallback for invalid).
#define ISSUE_A(AB, TARR, D) do {                                                \
    if (SKIP) {                                                                  \
      bool _anyv = (TARR[0] >= 0);                                               \
      _Pragma("unroll") for (int _m = 1; _m < MT; ++_m)                          \
        _anyv = _anyv || (TARR[_m] >= 0);                                        \
      D = (__ballot(_anyv) != 0ull);                                             \
    }                                                                            \
    _Pragma("unroll") for (int _m = 0; _m < MT; ++_m) {                          \
      const unsigned short* _s = Xb + (size_t)(TARR[_m] < 0 ? zrow : TARR[_m]) * ROWS + loff; \
      _Pragma("unroll") for (int kk = 0; kk < KK; ++kk)                          \
        AB[_m][kk] = *reinterpret_cast<const bf16x8*>(_s + kk * 32);             \
    }                                                                            \
  } while (0)

// Cooperative LDS staging of the 2 B sub-tiles (KB, KB+1) into PB.
#define STAGE_B2(KB, PB) do {                                                    \
    _Pragma("unroll") for (int _s = 0; _s < 2; ++_s) {                           \
      if ((KB) + _s <= MAXK) {                                                   \
        size_t _kb = (size_t)((KB) + _s) * (size_t)SZ;                           \
        _Pragma("unroll") for (int _j = 0; _j < PER; ++_j) {                     \
          int _c = w * PER + _j;                                                 \
          const unsigned char* _gp = WpB + _kb + (size_t)_c * 1024 + (size_t)l * 16; \
          __builtin_amdgcn_global_load_lds(                                      \
              (const __attribute__((address_space(1))) void*)_gp,                \
              (__attribute__((address_space(3))) void*)((PB) + _s * SZ + _c * 1024), 16, 0, 0); \
        }                                                                        \
      }                                                                          \
    }                                                                            \
  } while (0)

// ds_read B fragments from BCUR + MFMA on buffer AB (per-wave skip if empty;
// contains NO vmcnt ops, so skipping cannot break the barrier count).
#define STEP_CORE(BCUR, AB, D) do {                                              \
    if (!SKIP || (D)) {                                                          \
      _Pragma("unroll") for (int kk = 0; kk < KK; ++kk)                          \
        _Pragma("unroll") for (int nt = 0; nt < NT; ++nt) {                      \
          bf16x8 b = *reinterpret_cast<const bf16x8*>(&(BCUR)[(nt * KK + kk) * 1024 + l * 16]); \
          _Pragma("unroll") for (int _m = 0; _m < MT; ++_m)                      \
            acc[_m][nt] = __builtin_amdgcn_mfma_f32_16x16x32_bf16(AB[_m][kk], b, acc[_m][nt], 0, 0, 0); \
        }                                                                        \
    }                                                                            \
  } while (0)

// Counted-vmcnt barrier (T3/T4): stage issued FIRST in group; exactly NWAIT
// loads issued after it; vmcnt(NWAIT) completes the stage while prefetches
// stay in flight. No vmcnt(0) drain in the main loop.
#define GROUP_BARRIER() do {                                                     \
    __builtin_amdgcn_sched_barrier(0);                                           \
    asm volatile("s_waitcnt vmcnt(%0)" :: "n"(NWAIT) : "memory");                \
    __builtin_amdgcn_sched_barrier(0);                                           \
    __builtin_amdgcn_s_barrier();                                                \
  } while (0)

// Block = 4 waves x MT*16 rows, lockstep over steps in groups of 2. B
// double-buffered in LDS via global_load_lds; A ping-pong 2 steps ahead; tab 4
// ahead; counted-vmcnt barriers. PAIRED (conv1, CI=16): one step = TWO kernel
// offsets packed into K=32 (14 steps); lanes lg<2 gather k=2s, lg>=2 k=2s+1.
// (R15 config == measured best, 634 us total.)
template<int KK, int NT, int MT, bool SKIP, bool PAIRED>
__global__ __launch_bounds__(256, 4) void conv_mfma_kernel(
    const unsigned short* __restrict__ Xb, const unsigned short* __restrict__ Wp,
    const int* __restrict__ tab, int maxo, int zrow,
    const int* __restrict__ n_ptr, int n_cap,
    unsigned short* __restrict__ outb, float* __restrict__ outf) {
  const int CO = NT * 16;
  const int ROWS = PAIRED ? 16 : KK * 32;  // shorts per X row
  const int RPW = 16 * MT;                 // rows per wave
  constexpr int PER = (KK * NT) / 4;       // 1KB staging chunks per wave per sub-tile
  constexpr int SZ = KK * NT * 1024;       // bytes per B sub-tile
  constexpr int MAXK = PAIRED ? 13 : 26;   // last step index
  constexpr int GROUPS = PAIRED ? 6 : 13;  // full 2-step groups before tail
  constexpr int NWAIT = 2 * MT * KK + 2 * MT;  // loads issued after the stage

  __shared__ __align__(16) unsigned char Blds[2][2][SZ];

  int bid = blockIdx.x;
  { // bijective XCD-aware swizzle (m204)
    int nwg = gridDim.x;
    int q = nwg >> 3, r = nwg & 7;
    int xcd = bid & 7, orig = bid >> 3;
    bid = (xcd < r ? xcd * (q + 1) : r * (q + 1) + (xcd - r) * q) + orig;
  }

  int w = threadIdx.x >> 6, l = threadIdx.x & 63;
  int n_rows = n_cap;
  if (n_ptr) { int nv = n_ptr[0]; if (nv < n_rows) n_rows = nv; }
  if (bid * 4 * RPW >= n_rows) return;  // block-uniform exit (before any barrier)
  int lr = l & 15, lg = l >> 4;
  int klb = lg >> 1;                    // PAIRED: which of the 2 packed k's
  int loff = PAIRED ? (lg & 1) * 8 : lg * 8;  // short offset within X row
  int wbase = bid * 4 * RPW + w * RPW;

  // rows clamped (not predicated) so every load always issues -> exact counts
  int rowm[MT];
#pragma unroll
  for (int m = 0; m < MT; ++m) {
    int r = wbase + m * 16 + lr;
    rowm[m] = r < n_rows ? r : (n_rows - 1);
  }

  const unsigned char* WpB = (const unsigned char*)Wp;

  f32x4 acc[MT][NT] = {};
  bf16x8 a0[MT][KK], a1[MT][KK];
  int tE[MT], tO[MT];
  bool dE = true, dO = true;

  // ---- prologue: stage group 0 (steps 0,1); A(0),A(1); tab(2),tab(3) ----
  LDTAB(0, tE);
  LDTAB(1, tO);
  STAGE_B2(0, &Blds[0][0][0]);
  __builtin_amdgcn_sched_barrier(0);
  ISSUE_A(a0, tE, dE);
  ISSUE_A(a1, tO, dO);
  LDTAB(2, tE);
  LDTAB(3, tO);
  GROUP_BARRIER();

  // ---- GROUPS full groups, one counted-vmcnt barrier per group ----
#pragma unroll 1
  for (int g = 0; g < GROUPS; ++g) {
    int kb = g * 2;
    unsigned char* bc = &Blds[g & 1][0][0];
    unsigned char* bn = &Blds[(g + 1) & 1][0][0];
    STAGE_B2(kb + 2, bn);
    __builtin_amdgcn_sched_barrier(0);
    STEP_CORE(bc + 0 * SZ, a0, dE); ISSUE_A(a0, tE, dE); LDTAB(kb + 4, tE);
    STEP_CORE(bc + 1 * SZ, a1, dO); ISSUE_A(a1, tO, dO); LDTAB(kb + 5, tO);
    GROUP_BARRIER();
  }
  // ---- tail: non-paired = step 26; paired = steps 12,13 ----
  {
    unsigned char* bt = &Blds[GROUPS & 1][0][0];
    STEP_CORE(bt + 0 * SZ, a0, dE);
    if (PAIRED) STEP_CORE(bt + 1 * SZ, a1, dO);
  }

#pragma unroll
  for (int mt = 0; mt < MT; ++mt) {
    int r0 = wbase + mt * 16 + lg * 4;
#pragma unroll
    for (int rr = 0; rr < 4; ++rr) {
      int row = r0 + rr;
      if (row < n_rows) {
#pragma unroll
        for (int nt = 0; nt < NT; ++nt) {
          size_t off = (size_t)row * CO + nt * 16 + lr;
          if (outf) outf[off] = acc[mt][nt][rr];
          else outb[off] = f2bf(acc[mt][nt][rr]);
        }
      }
    }
  }
}

// BN stats/apply: R15-proven scalar forms (vectorized variants regressed in R16).
__global__ void bn_stats_kernel(const unsigned short* __restrict__ xb,
                                const int* __restrict__ n_ptr, int n_cap,
                                float* __restrict__ stats) {
  int c = threadIdx.x & 63, q = threadIdx.x >> 6;
  int n = n_ptr[0]; if (n > n_cap) n = n_cap;
  float s = 0.f, ss = 0.f;
  for (int r = blockIdx.x * 4 + q; r < n; r += gridDim.x * 4) {
    float v = bf2f(xb[(size_t)r * 64 + c]);
    s += v; ss += v * v;
  }
  __shared__ float ls[8][64];
  ls[q][c] = s; ls[4 + q][c] = ss;
  __syncthreads();
  if (q == 0) {
    s = ls[0][c] + ls[1][c] + ls[2][c] + ls[3][c];
    ss = ls[4][c] + ls[5][c] + ls[6][c] + ls[7][c];
    atomicAdd(&stats[c], s);
    atomicAdd(&stats[64 + c], ss);
  }
}

__global__ void bn_apply_kernel(unsigned short* __restrict__ xb,
                                const int* __restrict__ n_ptr, int n_cap,
                                const float* __restrict__ stats,
                                const float* __restrict__ gamma, const float* __restrict__ beta) {
  int c = threadIdx.x & 63, q = threadIdx.x >> 6;
  int n = n_ptr[0]; if (n > n_cap) n = n_cap;
  float inv_n = 1.f / (float)n;
  float m = stats[c] * inv_n;
  float var = stats[64 + c] * inv_n - m * m;
  float sc = gamma[c] * rsqrtf(var + 1e-5f);
  float sh = beta[c] - m * sc;
  for (int r = blockIdx.x * 4 + q; r < n; r += gridDim.x * 4) {
    size_t off = (size_t)r * 64 + c;
    float v = bf2f(xb[off]) * sc + sh;
    xb[off] = f2bf(v > 0.f ? v : 0.f);
  }
}

extern "C" void kernel_launch(void* const* d_in, const int* in_sizes, int n_in,
                              void* d_out, int out_size, void* d_ws, size_t ws_size,
                              hipStream_t stream) {
  const float* feats  = (const float*)d_in[0];
  const float* W1     = (const float*)d_in[1];
  const float* g1     = (const float*)d_in[2];
  const float* b1     = (const float*)d_in[3];
  const float* W2     = (const float*)d_in[4];
  const float* g2     = (const float*)d_in[5];
  const float* b2     = (const float*)d_in[6];
  const float* W3     = (const float*)d_in[7];
  const int* p1_in    = (const int*)d_in[8];
  const int* p1_out   = (const int*)d_in[9];
  const int* p2_in    = (const int*)d_in[10];
  const int* p2_out   = (const int*)d_in[11];
  const int* d_n1     = (const int*)d_in[12];
  float* out = (float*)d_out;

  const int N  = in_sizes[0] / 16;     // 200000
  const int P1 = in_sizes[8] / 27;
  const int P2 = in_sizes[10] / 27;
  long KP1 = in_sizes[8];
  int n1b = (int)(KP1 < 980100 ? KP1 : 980100);   // n1 <= min(#pairs1, out-grid size)
  int maxo = n1b > N ? n1b : N;

  char* p = (char*)d_ws;
  auto alloc = [&](size_t bytes) -> char* {
    char* r = p; p += (bytes + 255) & ~(size_t)255; return r;
  };
  unsigned short* featsb = (unsigned short*)alloc((size_t)(N + 1) * 16 * 2);  // compact
  unsigned short* x1b    = (unsigned short*)alloc((size_t)(n1b + 1) * 64 * 2);
  unsigned short* x2b    = (unsigned short*)alloc((size_t)(n1b + 1) * 64 * 2);
  unsigned short* W1p    = (unsigned short*)alloc((size_t)14 * 4 * 512 * 2);  // paired
  unsigned short* W2p    = (unsigned short*)alloc((size_t)27 * 4 * 2 * 512 * 2);
  unsigned short* W3p    = (unsigned short*)alloc((size_t)27 * 2 * 2 * 512 * 2);
  int*   tab   = (int*)alloc((size_t)maxo * 27 * 4);
  float* stats = (float*)alloc(256 * 4);
  if ((size_t)(p - (char*)d_ws) > ws_size) return;  // workspace insufficient -> fail visibly

  // zero-init: feats zero-row, the two x zero-rows, BN stats
  hipMemsetAsync(featsb + (size_t)N * 16, 0, 16 * 2, stream);
  hipMemsetAsync(x1b + (size_t)n1b * 64, 0, 64 * 2, stream);
  hipMemsetAsync(x2b + (size_t)n1b * 64, 0, 64 * 2, stream);
  hipMemsetAsync(stats, 0, 256 * 4, stream);

  cvt_feats_kernel<<<(N * 16 + 255) / 256, 256, 0, stream>>>(feats, featsb, N * 16);
  pack_w_paired_kernel<<<(14 * 4 * 512 + 255) / 256, 256, 0, stream>>>(W1, W1p, 64, 4);
  pack_w_kernel<<<(27 * 4 * 2 * 512 + 255) / 256, 256, 0, stream>>>(W2, W2p, 64, 64, 4, 2);
  pack_w_kernel<<<(27 * 2 * 2 * 512 + 255) / 256, 256, 0, stream>>>(W3, W3p, 64, 32, 2, 2);

  // ---- stage 1: SparseConv3d 16->64 (sparse tab, PAIRED k: 14 steps) ----
  hipMemsetAsync(tab, 0xFF, (size_t)n1b * 27 * 4, stream);
  build_table_kernel<<<dim3((P1 + 255) / 256, 27), 256, 0, stream>>>(
      p1_in, p1_out, P1, n1b, tab, d_n1, n1b);
  conv_mfma_kernel<1, 4, 2, true, true><<<(n1b + 127) / 128, 256, 0, stream>>>(
      featsb, W1p, tab, n1b, N, d_n1, n1b, x1b, nullptr);
  bn_stats_kernel<<<1024, 256, 0, stream>>>(x1b, d_n1, n1b, stats);
  bn_apply_kernel<<<2048, 256, 0, stream>>>(x1b, d_n1, n1b, stats, g1, b1);

  // ---- stage 2: SubMConv3d 64->64 (dense tab -> SKIP=false) ----
  hipMemsetAsync(tab, 0xFF, (size_t)n1b * 27 * 4, stream);
  build_table_kernel<<<dim3((P2 + 255) / 256, 27), 256, 0, stream>>>(
      p2_in, p2_out, P2, n1b, tab, d_n1, n1b);
  conv_mfma_kernel<2, 4, 2, false, false><<<(n1b + 127) / 128, 256, 0, stream>>>(
      x1b, W2p, tab, n1b, n1b, d_n1, n1b, x2b, nullptr);
  bn_stats_kernel<<<1024, 256, 0, stream>>>(x2b, d_n1, n1b, stats + 128);
  bn_apply_kernel<<<2048, 256, 0, stream>>>(x2b, d_n1, n1b, stats + 128, g2, b2);

  // ---- stage 3: SparseInverseConv3d 64->32 (pairs swapped, sparse) ----
  hipMemsetAsync(tab, 0xFF, (size_t)N * 27 * 4, stream);
  build_table_kernel<<<dim3((P1 + 255) / 256, 27), 256, 0, stream>>>(
      p1_out, p1_in, P1, N, tab, nullptr, N);
  conv_mfma_kernel<2, 2, 2, true, false><<<(N + 127) / 128, 256, 0, stream>>>(
      x2b, W3p, tab, N, n1b, nullptr, N, nullptr, out);
}

// Round 20
// 591.961 us; speedup vs baseline: 1.1185x; 1.0711x over previous
//
#include <hip/hip_runtime.h>
#include <hip/hip_bf16.h>

typedef __bf16 bf16x8 __attribute__((ext_vector_type(8)));
typedef float f32x4 __attribute__((ext_vector_type(4)));

__device__ __forceinline__ unsigned short f2bf(float x) {
  union { float f; unsigned int u; } v; v.f = x;
  unsigned int r = (v.u + 0x7FFFu + ((v.u >> 16) & 1u)) >> 16;
  return (unsigned short)r;
}
__device__ __forceinline__ float bf2f(unsigned short u) {
  union { unsigned int u; float f; } v; v.u = ((unsigned int)u) << 16;
  return v.f;
}

// feats [N][16] f32 -> [N][16] bf16 COMPACT (row N zeroed separately = zrow)
__global__ void cvt_feats_kernel(const float* __restrict__ f, unsigned short* __restrict__ fb, int n16) {
  int t = blockIdx.x * 256 + threadIdx.x;
  if (t >= n16) return;
  fb[t] = f2bf(f[t]);
}

// Pack W[k][CI][CO] f32 into MFMA B-fragment order (CI>=32 path, conv2/conv3)
__global__ void pack_w_kernel(const float* __restrict__ W, unsigned short* __restrict__ Wp,
                              int CI, int CO, int NT, int KK) {
  int t = blockIdx.x * 256 + threadIdx.x;
  int total = 27 * NT * KK * 512;
  if (t >= total) return;
  int j = t & 7, l = (t >> 3) & 63;
  int g = t >> 9;
  int kk = g % KK; g /= KK;
  int nt = g % NT; int k = g / NT;
  int kg = kk * 32 + ((l >> 4) * 8) + j;
  int c = nt * 16 + (l & 15);
  float v = (kg < CI) ? W[((size_t)k * CI + kg) * CO + c] : 0.0f;
  Wp[t] = f2bf(v);
}

// Paired pack for conv1 (CI=16): tile g holds K-rows 0-15 = W[2g], 16-31 = W[2g+1].
__global__ void pack_w_paired_kernel(const float* __restrict__ W, unsigned short* __restrict__ Wp,
                                     int CO, int NT) {
  int t = blockIdx.x * 256 + threadIdx.x;
  int total = 14 * NT * 512;
  if (t >= total) return;
  int j = t & 7, l = (t >> 3) & 63;
  int g = t >> 9;
  int nt = g % NT; int gp = g / NT;
  int kg = ((l >> 4) * 8) + j;
  int k = 2 * gp + (kg >= 16 ? 1 : 0);
  int ci = kg & 15;
  int c = nt * 16 + (l & 15);
  float v = (k <= 26) ? W[((size_t)k * 16 + ci) * CO + c] : 0.0f;
  Wp[t] = f2bf(v);
}

// tab[k][o] = input index (scatter from pair lists; unique per (k,o) by construction)
__global__ void build_table_kernel(const int* __restrict__ pin, const int* __restrict__ pout,
                                   int P, int maxo, int* __restrict__ tab,
                                   const int* __restrict__ n_ptr, int n_cap) {
  int p = blockIdx.x * 256 + threadIdx.x;
  if (p >= P) return;
  int k = blockIdx.y;
  int n = n_cap;
  if (n_ptr) { int nv = n_ptr[0]; if (nv < n) n = nv; }
  size_t e = (size_t)k * P + p;
  int o = pout[e];
  if (o < n) tab[(size_t)k * maxo + o] = pin[e];
}

// Per-lane tab loads, UNCONDITIONAL (rows pre-clamped; k clamped but load still
// issued) -> vmcnt accounting at the barrier stays exact. PAIRED: lane's k =
// 2*step + klb; overflow (>26) forces TARR=-1 (zero row + zeroed B half).
#define LDTAB(KC_, TARR) do {                                                    \
    int _k2 = PAIRED ? (2 * (KC_) + klb) : (KC_);                                \
    int _kc = _k2 > 26 ? 26 : _k2;                                               \
    _Pragma("unroll") for (int _m = 0; _m < MT; ++_m) {                          \
      int _t = tab[(size_t)_kc * maxo + rowm[_m]];                               \
      TARR[_m] = (PAIRED && _k2 > 26) ? -1 : _t;                                 \
    }                                                                            \
  } while (0)

// Gather A fragments into AB from tab values TARR; sets D (SKIP only).
// Unconditional: exactly MT*KK loads per call (zrow fallback for invalid).
#define ISSUE_A(AB, TARR, D) do {                                                \
    if (SKIP) {                                                                  \
      bool _anyv = (TARR[0] >= 0);                                               \
      _Pragma("unroll") for (int _m = 1; _m < MT; ++_m)                          \
        _anyv = _anyv || (TARR[_m] >= 0);                                        \
      D = (__ballot(_anyv) != 0ull);                                             \
    }                                                                            \
    _Pragma("unroll") for (int _m = 0; _m < MT; ++_m) {                          \
      const unsigned short* _s = Xb + (size_t)(TARR[_m] < 0 ? zrow : TARR[_m]) * ROWS + loff; \
      _Pragma("unroll") for (int kk = 0; kk < KK; ++kk)                          \
        AB[_m][kk] = *reinterpret_cast<const bf16x8*>(_s + kk * 32);             \
    }                                                                            \
  } while (0)

// Cooperative LDS staging of the 2 B sub-tiles (KB, KB+1) into PB.
#define STAGE_B2(KB, PB) do {                                                    \
    _Pragma("unroll") for (int _s = 0; _s < 2; ++_s) {                           \
      if ((KB) + _s <= MAXK) {                                                   \
        size_t _kb = (size_t)((KB) + _s) * (size_t)SZ;                           \
        _Pragma("unroll") for (int _j = 0; _j < PER; ++_j) {                     \
          int _c = w * PER + _j;                                                 \
          const unsigned char* _gp = WpB + _kb + (size_t)_c * 1024 + (size_t)l * 16; \
          __builtin_amdgcn_global_load_lds(                                      \
              (const __attribute__((address_space(1))) void*)_gp,                \
              (__attribute__((address_space(3))) void*)((PB) + _s * SZ + _c * 1024), 16, 0, 0); \
        }                                                                        \
      }                                                                          \
    }                                                                            \
  } while (0)

// ds_read B fragments from BCUR + MFMA on buffer AB (per-wave skip if empty;
// contains NO vmcnt ops, so skipping cannot break the barrier count).
#define STEP_CORE(BCUR, AB, D) do {                                              \
    if (!SKIP || (D)) {                                                          \
      _Pragma("unroll") for (int kk = 0; kk < KK; ++kk)                          \
        _Pragma("unroll") for (int nt = 0; nt < NT; ++nt) {                      \
          bf16x8 b = *reinterpret_cast<const bf16x8*>(&(BCUR)[(nt * KK + kk) * 1024 + l * 16]); \
          _Pragma("unroll") for (int _m = 0; _m < MT; ++_m)                      \
            acc[_m][nt] = __builtin_amdgcn_mfma_f32_16x16x32_bf16(AB[_m][kk], b, acc[_m][nt], 0, 0, 0); \
        }                                                                        \
    }                                                                            \
  } while (0)

// Counted-vmcnt barrier (T3/T4): stage issued FIRST in group; exactly NWAIT
// loads issued after it; vmcnt(NWAIT) completes the stage while prefetches
// stay in flight. No vmcnt(0) drain in the main loop.
#define GROUP_BARRIER() do {                                                     \
    __builtin_amdgcn_sched_barrier(0);                                           \
    asm volatile("s_waitcnt vmcnt(%0)" :: "n"(NWAIT) : "memory");                \
    __builtin_amdgcn_sched_barrier(0);                                           \
    __builtin_amdgcn_s_barrier();                                                \
  } while (0)

// Block = 4 waves x MT*16 rows, lockstep over steps in groups of 2. B
// double-buffered in LDS via global_load_lds; A ping-pong 2 steps ahead; tab 4
// ahead; counted-vmcnt barriers. PAIRED (conv1): 2 offsets packed per K=32.
// NEW vs R19: optional fused BN-stats — epilogue accumulates per-column
// sum/sumsq from fp32 acc (shfl over lg + LDS block reduce + 128 global
// atomics/block), deleting the standalone bn_stats passes.
template<int KK, int NT, int MT, bool SKIP, bool PAIRED>
__global__ __launch_bounds__(256, 4) void conv_mfma_kernel(
    const unsigned short* __restrict__ Xb, const unsigned short* __restrict__ Wp,
    const int* __restrict__ tab, int maxo, int zrow,
    const int* __restrict__ n_ptr, int n_cap,
    unsigned short* __restrict__ outb, float* __restrict__ outf,
    float* __restrict__ stats_out) {
  const int CO = NT * 16;
  const int ROWS = PAIRED ? 16 : KK * 32;  // shorts per X row
  const int RPW = 16 * MT;                 // rows per wave
  constexpr int PER = (KK * NT) / 4;       // 1KB staging chunks per wave per sub-tile
  constexpr int SZ = KK * NT * 1024;       // bytes per B sub-tile
  constexpr int MAXK = PAIRED ? 13 : 26;   // last step index
  constexpr int GROUPS = PAIRED ? 6 : 13;  // full 2-step groups before tail
  constexpr int NWAIT = 2 * MT * KK + 2 * MT;  // loads issued after the stage

  __shared__ __align__(16) unsigned char Blds[2][2][SZ];
  __shared__ float bs[2][64];              // fused-stats block scratch (512B)

  int bid = blockIdx.x;
  { // bijective XCD-aware swizzle (m204)
    int nwg = gridDim.x;
    int q = nwg >> 3, r = nwg & 7;
    int xcd = bid & 7, orig = bid >> 3;
    bid = (xcd < r ? xcd * (q + 1) : r * (q + 1) + (xcd - r) * q) + orig;
  }

  int w = threadIdx.x >> 6, l = threadIdx.x & 63;
  int n_rows = n_cap;
  if (n_ptr) { int nv = n_ptr[0]; if (nv < n_rows) n_rows = nv; }
  if (bid * 4 * RPW >= n_rows) return;  // block-uniform exit (before any barrier)
  int lr = l & 15, lg = l >> 4;
  int klb = lg >> 1;                    // PAIRED: which of the 2 packed k's
  int loff = PAIRED ? (lg & 1) * 8 : lg * 8;  // short offset within X row
  int wbase = bid * 4 * RPW + w * RPW;

  if (stats_out && threadIdx.x < 128)   // zero stats scratch (synced by prologue barrier)
    bs[threadIdx.x >> 6][threadIdx.x & 63] = 0.f;

  // rows clamped (not predicated) so every load always issues -> exact counts
  int rowm[MT];
#pragma unroll
  for (int m = 0; m < MT; ++m) {
    int r = wbase + m * 16 + lr;
    rowm[m] = r < n_rows ? r : (n_rows - 1);
  }

  const unsigned char* WpB = (const unsigned char*)Wp;

  f32x4 acc[MT][NT] = {};
  bf16x8 a0[MT][KK], a1[MT][KK];
  int tE[MT], tO[MT];
  bool dE = true, dO = true;

  // ---- prologue: stage group 0 (steps 0,1); A(0),A(1); tab(2),tab(3) ----
  LDTAB(0, tE);
  LDTAB(1, tO);
  STAGE_B2(0, &Blds[0][0][0]);
  __builtin_amdgcn_sched_barrier(0);
  ISSUE_A(a0, tE, dE);
  ISSUE_A(a1, tO, dO);
  LDTAB(2, tE);
  LDTAB(3, tO);
  GROUP_BARRIER();

  // ---- GROUPS full groups, one counted-vmcnt barrier per group ----
#pragma unroll 1
  for (int g = 0; g < GROUPS; ++g) {
    int kb = g * 2;
    unsigned char* bc = &Blds[g & 1][0][0];
    unsigned char* bn = &Blds[(g + 1) & 1][0][0];
    STAGE_B2(kb + 2, bn);
    __builtin_amdgcn_sched_barrier(0);
    STEP_CORE(bc + 0 * SZ, a0, dE); ISSUE_A(a0, tE, dE); LDTAB(kb + 4, tE);
    STEP_CORE(bc + 1 * SZ, a1, dO); ISSUE_A(a1, tO, dO); LDTAB(kb + 5, tO);
    GROUP_BARRIER();
  }
  // ---- tail: non-paired = step 26; paired = steps 12,13 ----
  {
    unsigned char* bt = &Blds[GROUPS & 1][0][0];
    STEP_CORE(bt + 0 * SZ, a0, dE);
    if (PAIRED) STEP_CORE(bt + 1 * SZ, a1, dO);
  }

  // ---- epilogue: write-out + (optional) fused BN-stats partials ----
  float sS[NT] = {}, sQ[NT] = {};
#pragma unroll
  for (int mt = 0; mt < MT; ++mt) {
    int r0 = wbase + mt * 16 + lg * 4;
#pragma unroll
    for (int rr = 0; rr < 4; ++rr) {
      int row = r0 + rr;
      if (row < n_rows) {
#pragma unroll
        for (int nt = 0; nt < NT; ++nt) {
          float v = acc[mt][nt][rr];
          size_t off = (size_t)row * CO + nt * 16 + lr;
          if (outf) outf[off] = v;
          else outb[off] = f2bf(v);
          sS[nt] += v; sQ[nt] += v * v;
        }
      }
    }
  }
  if (stats_out) {
    // reduce over the 4 lg groups (stride-16 lanes share column nt*16+lr)
#pragma unroll
    for (int nt = 0; nt < NT; ++nt) {
      sS[nt] += __shfl_xor(sS[nt], 16); sS[nt] += __shfl_xor(sS[nt], 32);
      sQ[nt] += __shfl_xor(sQ[nt], 16); sQ[nt] += __shfl_xor(sQ[nt], 32);
    }
    if (l < 16) {
#pragma unroll
      for (int nt = 0; nt < NT; ++nt) {
        atomicAdd(&bs[0][nt * 16 + lr], sS[nt]);
        atomicAdd(&bs[1][nt * 16 + lr], sQ[nt]);
      }
    }
    __syncthreads();
    if (threadIdx.x < 128) {
      int h = threadIdx.x >> 6, c = threadIdx.x & 63;
      atomicAdd(&stats_out[h * 64 + c], bs[h][c]);
    }
  }
}

// BN stats (standalone; now unused for stages 1/2 — kept for reference) and
// apply: R15-proven scalar forms.
__global__ void bn_apply_kernel(unsigned short* __restrict__ xb,
                                const int* __restrict__ n_ptr, int n_cap,
                                const float* __restrict__ stats,
                                const float* __restrict__ gamma, const float* __restrict__ beta) {
  int c = threadIdx.x & 63, q = threadIdx.x >> 6;
  int n = n_ptr[0]; if (n > n_cap) n = n_cap;
  float inv_n = 1.f / (float)n;
  float m = stats[c] * inv_n;
  float var = stats[64 + c] * inv_n - m * m;
  float sc = gamma[c] * rsqrtf(var + 1e-5f);
  float sh = beta[c] - m * sc;
  for (int r = blockIdx.x * 4 + q; r < n; r += gridDim.x * 4) {
    size_t off = (size_t)r * 64 + c;
    float v = bf2f(xb[off]) * sc + sh;
    xb[off] = f2bf(v > 0.f ? v : 0.f);
  }
}

extern "C" void kernel_launch(void* const* d_in, const int* in_sizes, int n_in,
                              void* d_out, int out_size, void* d_ws, size_t ws_size,
                              hipStream_t stream) {
  const float* feats  = (const float*)d_in[0];
  const float* W1     = (const float*)d_in[1];
  const float* g1     = (const float*)d_in[2];
  const float* b1     = (const float*)d_in[3];
  const float* W2     = (const float*)d_in[4];
  const float* g2     = (const float*)d_in[5];
  const float* b2     = (const float*)d_in[6];
  const float* W3     = (const float*)d_in[7];
  const int* p1_in    = (const int*)d_in[8];
  const int* p1_out   = (const int*)d_in[9];
  const int* p2_in    = (const int*)d_in[10];
  const int* p2_out   = (const int*)d_in[11];
  const int* d_n1     = (const int*)d_in[12];
  float* out = (float*)d_out;

  const int N  = in_sizes[0] / 16;     // 200000
  const int P1 = in_sizes[8] / 27;
  const int P2 = in_sizes[10] / 27;
  long KP1 = in_sizes[8];
  int n1b = (int)(KP1 < 980100 ? KP1 : 980100);   // n1 <= min(#pairs1, out-grid size)
  int maxo = n1b > N ? n1b : N;

  char* p = (char*)d_ws;
  auto alloc = [&](size_t bytes) -> char* {
    char* r = p; p += (bytes + 255) & ~(size_t)255; return r;
  };
  unsigned short* featsb = (unsigned short*)alloc((size_t)(N + 1) * 16 * 2);  // compact
  unsigned short* x1b    = (unsigned short*)alloc((size_t)(n1b + 1) * 64 * 2);
  unsigned short* x2b    = (unsigned short*)alloc((size_t)(n1b + 1) * 64 * 2);
  unsigned short* W1p    = (unsigned short*)alloc((size_t)14 * 4 * 512 * 2);  // paired
  unsigned short* W2p    = (unsigned short*)alloc((size_t)27 * 4 * 2 * 512 * 2);
  unsigned short* W3p    = (unsigned short*)alloc((size_t)27 * 2 * 2 * 512 * 2);
  int*   tab   = (int*)alloc((size_t)maxo * 27 * 4);
  float* stats = (float*)alloc(256 * 4);
  if ((size_t)(p - (char*)d_ws) > ws_size) return;  // workspace insufficient -> fail visibly

  // zero-init: feats zero-row, the two x zero-rows, BN stats
  hipMemsetAsync(featsb + (size_t)N * 16, 0, 16 * 2, stream);
  hipMemsetAsync(x1b + (size_t)n1b * 64, 0, 64 * 2, stream);
  hipMemsetAsync(x2b + (size_t)n1b * 64, 0, 64 * 2, stream);
  hipMemsetAsync(stats, 0, 256 * 4, stream);

  cvt_feats_kernel<<<(N * 16 + 255) / 256, 256, 0, stream>>>(feats, featsb, N * 16);
  pack_w_paired_kernel<<<(14 * 4 * 512 + 255) / 256, 256, 0, stream>>>(W1, W1p, 64, 4);
  pack_w_kernel<<<(27 * 4 * 2 * 512 + 255) / 256, 256, 0, stream>>>(W2, W2p, 64, 64, 4, 2);
  pack_w_kernel<<<(27 * 2 * 2 * 512 + 255) / 256, 256, 0, stream>>>(W3, W3p, 64, 32, 2, 2);

  // ---- stage 1: SparseConv3d 16->64 (sparse tab, PAIRED; fused BN-stats) ----
  hipMemsetAsync(tab, 0xFF, (size_t)n1b * 27 * 4, stream);
  build_table_kernel<<<dim3((P1 + 255) / 256, 27), 256, 0, stream>>>(
      p1_in, p1_out, P1, n1b, tab, d_n1, n1b);
  conv_mfma_kernel<1, 4, 2, true, true><<<(n1b + 127) / 128, 256, 0, stream>>>(
      featsb, W1p, tab, n1b, N, d_n1, n1b, x1b, nullptr, stats);
  bn_apply_kernel<<<2048, 256, 0, stream>>>(x1b, d_n1, n1b, stats, g1, b1);

  // ---- stage 2: SubMConv3d 64->64 (dense tab; fused BN-stats) ----
  hipMemsetAsync(tab, 0xFF, (size_t)n1b * 27 * 4, stream);
  build_table_kernel<<<dim3((P2 + 255) / 256, 27), 256, 0, stream>>>(
      p2_in, p2_out, P2, n1b, tab, d_n1, n1b);
  conv_mfma_kernel<2, 4, 2, false, false><<<(n1b + 127) / 128, 256, 0, stream>>>(
      x1b, W2p, tab, n1b, n1b, d_n1, n1b, x2b, nullptr, stats + 128);
  bn_apply_kernel<<<2048, 256, 0, stream>>>(x2b, d_n1, n1b, stats + 128, g2, b2);

  // ---- stage 3: SparseInverseConv3d 64->32 (pairs swapped, sparse) ----
  hipMemsetAsync(tab, 0xFF, (size_t)N * 27 * 4, stream);
  build_table_kernel<<<dim3((P1 + 255) / 256, 27), 256, 0, stream>>>(
      p1_out, p1_in, P1, N, tab, nullptr, N);
  conv_mfma_kernel<2, 2, 2, true, false><<<(N + 127) / 128, 256, 0, stream>>>(
      x2b, W3p, tab, N, n1b, nullptr, N, nullptr, out, nullptr);
}